// Round 4
// baseline (392.680 us; speedup 1.0000x reference)
//
#include <hip/hip_runtime.h>

#define VOCAB 30000
#define MPAD  30080   // 235 * 128

typedef __attribute__((ext_vector_type(8))) short bf16x8;
typedef __attribute__((ext_vector_type(4))) float f32x4;

__device__ __forceinline__ unsigned short f2bf(float f) {
    unsigned int u = __builtin_bit_cast(unsigned int, f);
    u += 0x7fffu + ((u >> 16) & 1u);          // round-to-nearest-even
    return (unsigned short)(u >> 16);
}
__device__ __forceinline__ float bf2f(unsigned int h) {
    unsigned int u = h << 16;
    return __builtin_bit_cast(float, u);
}

__device__ __forceinline__ void async16(const void* g, void* l) {
    __builtin_amdgcn_global_load_lds(
        (__attribute__((address_space(1))) void*)g,
        (__attribute__((address_space(3))) void*)l, 16, 0, 0);
}

// ---------------- compaction ----------------
// flags relies on the harness's 0xAA ws poison: "marked" == exactly 1.
// Also zeroes cnt and norm2 (82k threads >= VOCAB).
__global__ void comp_mark(const int* __restrict__ ingrs, const int* __restrict__ lengths,
                          int* __restrict__ flags, int* __restrict__ cnt,
                          float* __restrict__ norm2)
{
    const int i = blockIdx.x * 256 + threadIdx.x;   // < ceil(4096*20/256)*256
    if (i < VOCAB) norm2[i] = 0.f;
    if (i == 0) *cnt = 0;
    if (i >= 4096 * 20) return;
    const int b = i / 20;
    const int l = i - b * 20;
    if (l < lengths[b]) flags[ingrs[i]] = 1;
}

// assign compact slots (order irrelevant -> atomicAdd, no prefix sum)
__global__ void comp_assign(const int* __restrict__ flags, int* __restrict__ remap,
                            int* __restrict__ cnt)
{
    const int i = blockIdx.x * 256 + threadIdx.x;
    if (i < VOCAB && flags[i] == 1) remap[i] = atomicAdd(cnt, 1);
}

// ---------------- prep kernels ----------------

// A1[remap[id]][k] = bf16(relu(W1[id][k] + b1[k])) for flagged ids.
__global__ __launch_bounds__(256)
void prep_a1c(const float* __restrict__ W1, const float* __restrict__ b1,
              const int* __restrict__ flags, const int* __restrict__ remap,
              unsigned short* __restrict__ A1)
{
    const int tid = threadIdx.x;
    const int id  = blockIdx.x * 2 + (tid >> 7);     // < VOCAB
    if (flags[id] != 1) return;
    const int row = remap[id];
    const int k4  = (tid & 127) * 4;
    const float4 w  = *(const float4*)(W1 + (size_t)id * 512 + k4);
    const float4 bb = *(const float4*)(b1 + k4);
    unsigned short o[4];
    o[0] = f2bf(fmaxf(w.x + bb.x, 0.f));
    o[1] = f2bf(fmaxf(w.y + bb.y, 0.f));
    o[2] = f2bf(fmaxf(w.z + bb.z, 0.f));
    o[3] = f2bf(fmaxf(w.w + bb.w, 0.f));
    *(uint2*)(A1 + (size_t)row * 512 + k4) = *(const uint2*)o;
}

// out[n][k] = bf16(in[k][n]); in is [K x Nin] f32, out is [Nout x K] bf16,
// cols n >= Nin zero-padded. LDS-tiled, coalesced both sides.
__global__ __launch_bounds__(256)
void transpose_to_bf16(const float* __restrict__ in, unsigned short* __restrict__ out,
                       int K, int Nin)
{
    __shared__ float t[64][65];
    const int n0  = blockIdx.x * 64;
    const int k0  = blockIdx.y * 64;
    const int tid = threadIdx.x;
#pragma unroll
    for (int p = 0; p < 16; ++p) {
        const int lin = p * 256 + tid;
        const int kk = lin >> 6, nn = lin & 63;
        const int n = n0 + nn;
        t[kk][nn] = (n < Nin) ? in[(size_t)(k0 + kk) * Nin + n] : 0.f;
    }
    __syncthreads();
#pragma unroll
    for (int p = 0; p < 16; ++p) {
        const int lin = p * 256 + tid;
        const int nn = lin >> 6, kk = lin & 63;
        out[(size_t)(n0 + nn) * K + k0 + kk] = f2bf(t[kk][nn]);
    }
}

// ---------------- bf16 MFMA GEMM, BK=64, XOR-swizzled LDS, M early-exit ----
// C[M x N] = op(A[M x K] @ BT^T); BT is [N x K]. N%128==0, K%64==0.
// Effective M = round128(*cnt). NORM: accumulate per-row sum-of-squares
// (post-bias, pre-bf16-round) into norm2[] via atomicAdd.
template<int RELU, int NORM>
__global__ __launch_bounds__(256)
void gemm_bf16(const unsigned short* __restrict__ A,
               const unsigned short* __restrict__ BT,
               const float* __restrict__ bias, int bias_n,
               unsigned short* __restrict__ C,
               int K, int N, const int* __restrict__ cnt,
               float* __restrict__ norm2)
{
    const int m0 = blockIdx.y * 128;
    const int mc = (*cnt + 127) & ~127;
    if (m0 >= mc) return;

    __shared__ __align__(16) unsigned short As[128 * 64];
    __shared__ __align__(16) unsigned short Bs[128 * 64];

    const int tid  = threadIdx.x;
    const int lane = tid & 63;
    const int wid  = tid >> 6;
    const int wr   = wid >> 1;          // wave row 0..1 (64-row span)
    const int wc   = wid & 1;           // wave col 0..1 (64-col span)
    const int n0   = blockIdx.x * 128;

    const int q  = lane >> 4;           // 0..3
    const int ml = lane & 15;

    f32x4 acc[4][4];
    const f32x4 zero = {0.f, 0.f, 0.f, 0.f};
#pragma unroll
    for (int i = 0; i < 4; ++i)
#pragma unroll
        for (int j = 0; j < 4; ++j) acc[i][j] = zero;

    // staging: wave w stages groups 4w..4w+3 (8 rows each) of A and of B.
    // LDS row r holds its 8 16-B k-chunks permuted: chunk kc at pos kc^(r&7).
    const int rg = lane >> 3;                    // row within group, 0..7
    const int kc = (lane & 7) ^ rg;              // swizzled global k-chunk
    const unsigned short* pA = A  + (size_t)(m0 + wid * 32 + rg) * K + kc * 8;
    const unsigned short* pB = BT + (size_t)(n0 + wid * 32 + rg) * K + kc * 8;
    unsigned short* lA = &As[wid * 4 * 512 + lane * 8];
    unsigned short* lB = &Bs[wid * 4 * 512 + lane * 8];

    // fragment-read swizzle: chunk index (k32*4+q) ^ (row&7), row&7 == ml&7
    const int swz0 = (q ^ (ml & 7)) * 8;         // k-half 0; ^32 elems for half 1

    for (int k0 = 0; k0 < K; k0 += 64) {
#pragma unroll
        for (int gg = 0; gg < 4; ++gg) {
            async16(pA + (size_t)gg * 8 * K + k0, lA + gg * 512);
            async16(pB + (size_t)gg * 8 * K + k0, lB + gg * 512);
        }
        __syncthreads();   // drains vmcnt -> LDS tiles ready

        bf16x8 af[4], bfr[4];
#pragma unroll
        for (int t = 0; t < 4; ++t) {
            af[t]  = *(const bf16x8*)&As[(wr * 64 + t * 16 + ml) * 64 + swz0];
            bfr[t] = *(const bf16x8*)&Bs[(wc * 64 + t * 16 + ml) * 64 + swz0];
        }
#pragma unroll
        for (int i = 0; i < 4; ++i)
#pragma unroll
            for (int j = 0; j < 4; ++j)
                acc[i][j] = __builtin_amdgcn_mfma_f32_16x16x32_bf16(
                    af[i], bfr[j], acc[i][j], 0, 0, 0);
#pragma unroll
        for (int t = 0; t < 4; ++t) {
            af[t]  = *(const bf16x8*)&As[(wr * 64 + t * 16 + ml) * 64 + (swz0 ^ 32)];
            bfr[t] = *(const bf16x8*)&Bs[(wc * 64 + t * 16 + ml) * 64 + (swz0 ^ 32)];
        }
#pragma unroll
        for (int i = 0; i < 4; ++i)
#pragma unroll
            for (int j = 0; j < 4; ++j)
                acc[i][j] = __builtin_amdgcn_mfma_f32_16x16x32_bf16(
                    af[i], bfr[j], acc[i][j], 0, 0, 0);

        __syncthreads();   // protect LDS before next stage
    }

    // epilogue: D col = lane&15, row = (lane>>4)*4 + r  [m89/m91-verified layout]
#pragma unroll
    for (int i = 0; i < 4; ++i) {
#pragma unroll
        for (int r = 0; r < 4; ++r) {
            const int row = m0 + wr * 64 + i * 16 + q * 4 + r;
            float s = 0.f;
#pragma unroll
            for (int j = 0; j < 4; ++j) {
                const int col = n0 + wc * 64 + j * 16 + ml;
                float v = acc[i][j][r];
                v += (col < bias_n) ? bias[col] : 0.f;
                if (RELU) v = fmaxf(v, 0.f);
                if (NORM) s += v * v;
                C[(size_t)row * N + col] = f2bf(v);
            }
            if (NORM) {
                // reduce over the 16 lanes of this q-group (ml = low 4 bits)
                s += __shfl_xor(s, 1, 64);
                s += __shfl_xor(s, 2, 64);
                s += __shfl_xor(s, 4, 64);
                s += __shfl_xor(s, 8, 64);
                if (ml == 0) atomicAdd(&norm2[row], s);
            }
        }
    }
}

// ---------------- phase B: sync-free gather + scale + masked sum ----------
__global__ __launch_bounds__(256)
void gather_norm_sum(const int* __restrict__ ingrs, const int* __restrict__ lengths,
                     const int* __restrict__ remap, const float* __restrict__ norm2,
                     const unsigned short* __restrict__ Table, float* __restrict__ out)
{
    const int b   = blockIdx.x;
    const int tid = threadIdx.x;

    float acc[8];
#pragma unroll
    for (int j = 0; j < 8; ++j) acc[j] = 0.f;

    const int len = lengths[b];   // uniform per block
    for (int l = 0; l < len; ++l) {
        const int slot   = remap[ingrs[b * 20 + l]];
        const float invn = 1.0f / sqrtf(fmaxf(norm2[slot], 1e-24f));
        const uint4 u = *((const uint4*)(Table + (size_t)slot * 2048) + tid);
        float v[8];
        v[0] = bf2f(u.x & 0xffffu); v[1] = bf2f(u.x >> 16);
        v[2] = bf2f(u.y & 0xffffu); v[3] = bf2f(u.y >> 16);
        v[4] = bf2f(u.z & 0xffffu); v[5] = bf2f(u.z >> 16);
        v[6] = bf2f(u.w & 0xffffu); v[7] = bf2f(u.w >> 16);
#pragma unroll
        for (int j = 0; j < 8; ++j) acc[j] += v[j] * invn;
    }

    const size_t base = (size_t)b * 2047;
#pragma unroll
    for (int j = 0; j < 8; ++j) {
        const int col = tid * 8 + j;
        if (col < 2047) out[base + col] = acc[j];
    }
}

// ---------------- launch ----------------

extern "C" void kernel_launch(void* const* d_in, const int* in_sizes, int n_in,
                              void* d_out, int out_size, void* d_ws, size_t ws_size,
                              hipStream_t stream)
{
    const int*   ingrs   = (const int*)d_in[0];
    const int*   lengths = (const int*)d_in[1];
    const float* W1 = (const float*)d_in[2];
    const float* b1 = (const float*)d_in[3];
    const float* W2 = (const float*)d_in[4];
    const float* b2 = (const float*)d_in[5];
    const float* W3 = (const float*)d_in[6];
    const float* b3 = (const float*)d_in[7];
    float* out = (float*)d_out;

    // ws layout (byte offsets, 16B-aligned):
    //   A1    [MPAD x 512]  bf16 :           0 ..  30,801,920
    //   H2    [MPAD x 1024] bf16 :  30,801,920 ..  92,405,760
    //   Table [MPAD x 2048] bf16 :  92,405,760 .. 215,613,440
    //   W2T   [1024 x 512]  bf16 : 215,613,440 .. 216,662,016
    //   W3T   [2048 x 1024] bf16 : 216,662,016 .. 220,856,320
    //   flags [VOCAB] int        : 220,856,320 .. 220,976,320
    //   remap [VOCAB] int        : 220,976,320 .. 221,096,320
    //   cnt   [1] int            : 221,096,320 .. 221,096,324
    //   norm2 [VOCAB] f32        : 221,096,448 .. 221,216,448
    char* ws = (char*)d_ws;
    unsigned short* A1    = (unsigned short*)(ws);
    unsigned short* H2    = (unsigned short*)(ws + 30801920);
    unsigned short* Table = (unsigned short*)(ws + 92405760);
    unsigned short* W2T   = (unsigned short*)(ws + 215613440);
    unsigned short* W3T   = (unsigned short*)(ws + 216662016);
    int*            flags = (int*)(ws + 220856320);
    int*            remap = (int*)(ws + 220976320);
    int*            cnt   = (int*)(ws + 221096320);
    float*          norm2 = (float*)(ws + 221096448);

    comp_mark  <<<(4096 * 20 + 255) / 256, 256, 0, stream>>>(ingrs, lengths, flags, cnt, norm2);
    comp_assign<<<(VOCAB + 255) / 256, 256, 0, stream>>>(flags, remap, cnt);

    prep_a1c<<<VOCAB / 2, 256, 0, stream>>>(W1, b1, flags, remap, A1);
    // W2 [512 x 1024] -> W2T [1024 x 512]
    transpose_to_bf16<<<dim3(1024 / 64, 512 / 64), 256, 0, stream>>>(W2, W2T, 512, 1024);
    // W3 [1024 x 2047] -> W3T [2048 x 1024], col 2047 zero-padded
    transpose_to_bf16<<<dim3(2048 / 64, 1024 / 64), 256, 0, stream>>>(W3, W3T, 1024, 2047);

    // H2 = relu(A1 @ W2 + b2)   [mc x 1024]   (rows cnt..mc read poison A1: harmless)
    gemm_bf16<1, 0><<<dim3(1024 / 128, MPAD / 128), 256, 0, stream>>>(
        A1, W2T, b2, 1024, H2, 512, 1024, cnt, norm2);
    // Table = H2 @ W3 + b3      [mc x 2048], fused per-row sum-of-squares -> norm2
    gemm_bf16<0, 1><<<dim3(2048 / 128, MPAD / 128), 256, 0, stream>>>(
        H2, W3T, b3, 2047, Table, 1024, 2048, cnt, norm2);

    gather_norm_sum<<<4096, 256, 0, stream>>>(ingrs, lengths, remap, norm2, Table, out);
}

// Round 5
// 384.590 us; speedup vs baseline: 1.0210x; 1.0210x over previous
//
#include <hip/hip_runtime.h>

#define VOCAB 30000
#define MPAD  30080   // 235 * 128

typedef __attribute__((ext_vector_type(8))) short bf16x8;
typedef __attribute__((ext_vector_type(4))) float f32x4;

__device__ __forceinline__ unsigned short f2bf(float f) {
    unsigned int u = __builtin_bit_cast(unsigned int, f);
    u += 0x7fffu + ((u >> 16) & 1u);          // round-to-nearest-even
    return (unsigned short)(u >> 16);
}
__device__ __forceinline__ float bf2f(unsigned int h) {
    unsigned int u = h << 16;
    return __builtin_bit_cast(float, u);
}

__device__ __forceinline__ void async16(const void* g, void* l) {
    __builtin_amdgcn_global_load_lds(
        (__attribute__((address_space(1))) void*)g,
        (__attribute__((address_space(3))) void*)l, 16, 0, 0);
}

// ---------------- compaction ----------------
// flags relies on the harness's 0xAA ws poison: "marked" == exactly 1.
__global__ void comp_mark(const int* __restrict__ ingrs, const int* __restrict__ lengths,
                          int* __restrict__ flags, int* __restrict__ cnt)
{
    const int i = blockIdx.x * 256 + threadIdx.x;
    if (i == 0) *cnt = 0;
    if (i >= 4096 * 20) return;
    const int b = i / 20;
    const int l = i - b * 20;
    if (l < lengths[b]) flags[ingrs[i]] = 1;
}

// assign compact slots (order irrelevant -> atomicAdd, no prefix sum)
__global__ void comp_assign(const int* __restrict__ flags, int* __restrict__ remap,
                            int* __restrict__ cnt)
{
    const int i = blockIdx.x * 256 + threadIdx.x;
    if (i < VOCAB && flags[i] == 1) remap[i] = atomicAdd(cnt, 1);
}

// materialize per-token slots (kills one dependent-load hop in gather)
__global__ void comp_slots(const int* __restrict__ ingrs, const int* __restrict__ lengths,
                           const int* __restrict__ remap, int* __restrict__ slots)
{
    const int i = blockIdx.x * 256 + threadIdx.x;
    if (i >= 4096 * 20) return;
    const int b = i / 20;
    const int l = i - b * 20;
    if (l < lengths[b]) slots[i] = remap[ingrs[i]];
}

// ---------------- prep kernels ----------------

// A1[remap[id]][k] = bf16(relu(W1[id][k] + b1[k])) for flagged ids.
__global__ __launch_bounds__(256)
void prep_a1c(const float* __restrict__ W1, const float* __restrict__ b1,
              const int* __restrict__ flags, const int* __restrict__ remap,
              unsigned short* __restrict__ A1)
{
    const int tid = threadIdx.x;
    const int id  = blockIdx.x * 2 + (tid >> 7);     // < VOCAB
    if (flags[id] != 1) return;
    const int row = remap[id];
    const int k4  = (tid & 127) * 4;
    const float4 w  = *(const float4*)(W1 + (size_t)id * 512 + k4);
    const float4 bb = *(const float4*)(b1 + k4);
    unsigned short o[4];
    o[0] = f2bf(fmaxf(w.x + bb.x, 0.f));
    o[1] = f2bf(fmaxf(w.y + bb.y, 0.f));
    o[2] = f2bf(fmaxf(w.z + bb.z, 0.f));
    o[3] = f2bf(fmaxf(w.w + bb.w, 0.f));
    *(uint2*)(A1 + (size_t)row * 512 + k4) = *(const uint2*)o;
}

// out[n][k] = bf16(in[k][n]); in is [K x Nin] f32, out is [Nout x K] bf16,
// cols n >= Nin zero-padded. LDS-tiled, coalesced both sides.
__global__ __launch_bounds__(256)
void transpose_to_bf16(const float* __restrict__ in, unsigned short* __restrict__ out,
                       int K, int Nin)
{
    __shared__ float t[64][65];
    const int n0  = blockIdx.x * 64;
    const int k0  = blockIdx.y * 64;
    const int tid = threadIdx.x;
#pragma unroll
    for (int p = 0; p < 16; ++p) {
        const int lin = p * 256 + tid;
        const int kk = lin >> 6, nn = lin & 63;
        const int n = n0 + nn;
        t[kk][nn] = (n < Nin) ? in[(size_t)(k0 + kk) * Nin + n] : 0.f;
    }
    __syncthreads();
#pragma unroll
    for (int p = 0; p < 16; ++p) {
        const int lin = p * 256 + tid;
        const int nn = lin >> 6, kk = lin & 63;
        out[(size_t)(n0 + nn) * K + k0 + kk] = f2bf(t[kk][nn]);
    }
}

// ---------------- bf16 MFMA GEMM, BK=64, XOR-swizzled LDS, M early-exit ----
// (exact R3 structure: the fastest measured variant — no norm fusion)
__global__ __launch_bounds__(256)
void gemm_bf16(const unsigned short* __restrict__ A,
               const unsigned short* __restrict__ BT,
               const float* __restrict__ bias, int bias_n,
               unsigned short* __restrict__ C,
               int K, int N, int relu, const int* __restrict__ cnt)
{
    const int m0 = blockIdx.y * 128;
    const int mc = (*cnt + 127) & ~127;
    if (m0 >= mc) return;

    __shared__ __align__(16) unsigned short As[128 * 64];
    __shared__ __align__(16) unsigned short Bs[128 * 64];

    const int tid  = threadIdx.x;
    const int lane = tid & 63;
    const int wid  = tid >> 6;
    const int wr   = wid >> 1;          // wave row 0..1 (64-row span)
    const int wc   = wid & 1;           // wave col 0..1 (64-col span)
    const int n0   = blockIdx.x * 128;

    const int q  = lane >> 4;           // 0..3
    const int ml = lane & 15;

    f32x4 acc[4][4];
    const f32x4 zero = {0.f, 0.f, 0.f, 0.f};
#pragma unroll
    for (int i = 0; i < 4; ++i)
#pragma unroll
        for (int j = 0; j < 4; ++j) acc[i][j] = zero;

    // staging: wave w stages groups 4w..4w+3 (8 rows each) of A and of B.
    // LDS row r holds its 8 16-B k-chunks permuted: chunk kc at pos kc^(r&7).
    const int rg = lane >> 3;                    // row within group, 0..7
    const int kc = (lane & 7) ^ rg;              // swizzled global k-chunk
    const unsigned short* pA = A  + (size_t)(m0 + wid * 32 + rg) * K + kc * 8;
    const unsigned short* pB = BT + (size_t)(n0 + wid * 32 + rg) * K + kc * 8;
    unsigned short* lA = &As[wid * 4 * 512 + lane * 8];
    unsigned short* lB = &Bs[wid * 4 * 512 + lane * 8];

    // fragment-read swizzle: chunk index (k32*4+q) ^ (row&7), row&7 == ml&7
    const int swz0 = (q ^ (ml & 7)) * 8;         // k-half 0; ^32 elems for half 1

    for (int k0 = 0; k0 < K; k0 += 64) {
#pragma unroll
        for (int gg = 0; gg < 4; ++gg) {
            async16(pA + (size_t)gg * 8 * K + k0, lA + gg * 512);
            async16(pB + (size_t)gg * 8 * K + k0, lB + gg * 512);
        }
        __syncthreads();   // drains vmcnt -> LDS tiles ready

        bf16x8 af[4], bfr[4];
#pragma unroll
        for (int t = 0; t < 4; ++t) {
            af[t]  = *(const bf16x8*)&As[(wr * 64 + t * 16 + ml) * 64 + swz0];
            bfr[t] = *(const bf16x8*)&Bs[(wc * 64 + t * 16 + ml) * 64 + swz0];
        }
#pragma unroll
        for (int i = 0; i < 4; ++i)
#pragma unroll
            for (int j = 0; j < 4; ++j)
                acc[i][j] = __builtin_amdgcn_mfma_f32_16x16x32_bf16(
                    af[i], bfr[j], acc[i][j], 0, 0, 0);
#pragma unroll
        for (int t = 0; t < 4; ++t) {
            af[t]  = *(const bf16x8*)&As[(wr * 64 + t * 16 + ml) * 64 + (swz0 ^ 32)];
            bfr[t] = *(const bf16x8*)&Bs[(wc * 64 + t * 16 + ml) * 64 + (swz0 ^ 32)];
        }
#pragma unroll
        for (int i = 0; i < 4; ++i)
#pragma unroll
            for (int j = 0; j < 4; ++j)
                acc[i][j] = __builtin_amdgcn_mfma_f32_16x16x32_bf16(
                    af[i], bfr[j], acc[i][j], 0, 0, 0);

        __syncthreads();   // protect LDS before next stage
    }

    // epilogue: D col = lane&15, row = (lane>>4)*4 + r  [m89/m91-verified layout]
#pragma unroll
    for (int i = 0; i < 4; ++i) {
#pragma unroll
        for (int j = 0; j < 4; ++j) {
#pragma unroll
            for (int r = 0; r < 4; ++r) {
                const int row = m0 + wr * 64 + i * 16 + q * 4 + r;
                const int col = n0 + wc * 64 + j * 16 + ml;
                float v = acc[i][j][r];
                v += (col < bias_n) ? bias[col] : 0.f;
                if (relu) v = fmaxf(v, 0.f);
                C[(size_t)row * N + col] = f2bf(v);
            }
        }
    }
}

// ---------------- row_norms: one wave per Table row ----------------
__global__ __launch_bounds__(256)
void row_norms(const unsigned short* __restrict__ Table, const int* __restrict__ cnt,
               float* __restrict__ norm2)
{
    const int mc  = (*cnt + 127) & ~127;
    const int row = blockIdx.x * 4 + (threadIdx.x >> 6);
    if (row >= mc) return;
    const int lane = threadIdx.x & 63;
    const uint4* p = (const uint4*)(Table + (size_t)row * 2048);
    float s = 0.f;
#pragma unroll
    for (int c = 0; c < 4; ++c) {
        const uint4 u = p[c * 64 + lane];
        float v;
        v = bf2f(u.x & 0xffffu); s += v * v;  v = bf2f(u.x >> 16); s += v * v;
        v = bf2f(u.y & 0xffffu); s += v * v;  v = bf2f(u.y >> 16); s += v * v;
        v = bf2f(u.z & 0xffffu); s += v * v;  v = bf2f(u.z >> 16); s += v * v;
        v = bf2f(u.w & 0xffffu); s += v * v;  v = bf2f(u.w >> 16); s += v * v;
    }
#pragma unroll
    for (int off = 1; off < 64; off <<= 1) s += __shfl_xor(s, off, 64);
    if (lane == 0) norm2[row] = s;
}

// ---------------- phase B: pipelined sync-free gather + scale + sum --------
__global__ __launch_bounds__(256)
void gather_norm_sum(const int* __restrict__ lengths, const int* __restrict__ slots,
                     const float* __restrict__ norm2,
                     const unsigned short* __restrict__ Table, float* __restrict__ out)
{
    const int b   = blockIdx.x;
    const int tid = threadIdx.x;

    float acc[8];
#pragma unroll
    for (int j = 0; j < 8; ++j) acc[j] = 0.f;

    const int len = lengths[b];   // uniform per block
    if (len > 0) {
        int slot = slots[b * 20];
        float invn = 1.0f / sqrtf(fmaxf(norm2[slot], 1e-24f));
        uint4 u = *((const uint4*)(Table + (size_t)slot * 2048) + tid);
        for (int l = 0; l < len; ++l) {
            const uint4 cu = u;
            const float ci = invn;
            if (l + 1 < len) {                       // prefetch next row
                const int ns = slots[b * 20 + l + 1];
                invn = 1.0f / sqrtf(fmaxf(norm2[ns], 1e-24f));
                u = *((const uint4*)(Table + (size_t)ns * 2048) + tid);
            }
            acc[0] += bf2f(cu.x & 0xffffu) * ci;  acc[1] += bf2f(cu.x >> 16) * ci;
            acc[2] += bf2f(cu.y & 0xffffu) * ci;  acc[3] += bf2f(cu.y >> 16) * ci;
            acc[4] += bf2f(cu.z & 0xffffu) * ci;  acc[5] += bf2f(cu.z >> 16) * ci;
            acc[6] += bf2f(cu.w & 0xffffu) * ci;  acc[7] += bf2f(cu.w >> 16) * ci;
        }
    }

    const size_t base = (size_t)b * 2047;
#pragma unroll
    for (int j = 0; j < 8; ++j) {
        const int col = tid * 8 + j;
        if (col < 2047) out[base + col] = acc[j];
    }
}

// ---------------- launch ----------------

extern "C" void kernel_launch(void* const* d_in, const int* in_sizes, int n_in,
                              void* d_out, int out_size, void* d_ws, size_t ws_size,
                              hipStream_t stream)
{
    const int*   ingrs   = (const int*)d_in[0];
    const int*   lengths = (const int*)d_in[1];
    const float* W1 = (const float*)d_in[2];
    const float* b1 = (const float*)d_in[3];
    const float* W2 = (const float*)d_in[4];
    const float* b2 = (const float*)d_in[5];
    const float* W3 = (const float*)d_in[6];
    const float* b3 = (const float*)d_in[7];
    float* out = (float*)d_out;

    // ws layout (byte offsets, 16B-aligned):
    //   A1    [MPAD x 512]  bf16 :           0 ..  30,801,920
    //   H2    [MPAD x 1024] bf16 :  30,801,920 ..  92,405,760
    //   Table [MPAD x 2048] bf16 :  92,405,760 .. 215,613,440
    //   W2T   [1024 x 512]  bf16 : 215,613,440 .. 216,662,016
    //   W3T   [2048 x 1024] bf16 : 216,662,016 .. 220,856,320
    //   flags [VOCAB] int        : 220,856,320 .. 220,976,320
    //   remap [VOCAB] int        : 220,976,320 .. 221,096,320
    //   cnt   [1] int            : 221,096,320 .. 221,096,324
    //   norm2 [VOCAB] f32        : 221,096,448 .. 221,216,448
    //   slots [4096*20] int      : 221,216,448 .. 221,544,128
    char* ws = (char*)d_ws;
    unsigned short* A1    = (unsigned short*)(ws);
    unsigned short* H2    = (unsigned short*)(ws + 30801920);
    unsigned short* Table = (unsigned short*)(ws + 92405760);
    unsigned short* W2T   = (unsigned short*)(ws + 215613440);
    unsigned short* W3T   = (unsigned short*)(ws + 216662016);
    int*            flags = (int*)(ws + 220856320);
    int*            remap = (int*)(ws + 220976320);
    int*            cnt   = (int*)(ws + 221096320);
    float*          norm2 = (float*)(ws + 221096448);
    int*            slots = (int*)(ws + 221216448);

    comp_mark  <<<(4096 * 20 + 255) / 256, 256, 0, stream>>>(ingrs, lengths, flags, cnt);
    comp_assign<<<(VOCAB + 255) / 256, 256, 0, stream>>>(flags, remap, cnt);
    comp_slots <<<(4096 * 20 + 255) / 256, 256, 0, stream>>>(ingrs, lengths, remap, slots);

    prep_a1c<<<VOCAB / 2, 256, 0, stream>>>(W1, b1, flags, remap, A1);
    // W2 [512 x 1024] -> W2T [1024 x 512]
    transpose_to_bf16<<<dim3(1024 / 64, 512 / 64), 256, 0, stream>>>(W2, W2T, 512, 1024);
    // W3 [1024 x 2047] -> W3T [2048 x 1024], col 2047 zero-padded
    transpose_to_bf16<<<dim3(2048 / 64, 1024 / 64), 256, 0, stream>>>(W3, W3T, 1024, 2047);

    // H2 = relu(A1 @ W2 + b2)   [mc x 1024]   (rows cnt..mc read poison A1: harmless)
    gemm_bf16<<<dim3(1024 / 128, MPAD / 128), 256, 0, stream>>>(
        A1, W2T, b2, 1024, H2, 512, 1024, 1, cnt);
    // Table = H2 @ W3 + b3      [mc x 2048] (col 2047 is zero pad)
    gemm_bf16<<<dim3(2048 / 128, MPAD / 128), 256, 0, stream>>>(
        H2, W3T, b3, 2047, Table, 1024, 2048, 0, cnt);

    row_norms<<<MPAD / 4, 256, 0, stream>>>(Table, cnt, norm2);
    gather_norm_sum<<<4096, 256, 0, stream>>>(lengths, slots, norm2, Table, out);
}

// Round 6
// 359.088 us; speedup vs baseline: 1.0935x; 1.0710x over previous
//
#include <hip/hip_runtime.h>

#define VOCAB 30000
#define MPAD  30080   // 235 * 128

typedef __attribute__((ext_vector_type(8))) short bf16x8;
typedef __attribute__((ext_vector_type(4))) float f32x4;

__device__ __forceinline__ unsigned short f2bf(float f) {
    unsigned int u = __builtin_bit_cast(unsigned int, f);
    u += 0x7fffu + ((u >> 16) & 1u);          // round-to-nearest-even
    return (unsigned short)(u >> 16);
}
__device__ __forceinline__ float bf2f(unsigned int h) {
    unsigned int u = h << 16;
    return __builtin_bit_cast(float, u);
}

__device__ __forceinline__ void async16(const void* g, void* l) {
    __builtin_amdgcn_global_load_lds(
        (__attribute__((address_space(1))) void*)g,
        (__attribute__((address_space(3))) void*)l, 16, 0, 0);
}

// ---------------- compaction ----------------
// flags relies on the harness's 0xAA ws poison: "marked" == exactly 1.
__global__ void comp_mark(const int* __restrict__ ingrs, const int* __restrict__ lengths,
                          int* __restrict__ flags, int* __restrict__ cnt)
{
    const int i = blockIdx.x * 256 + threadIdx.x;
    if (i == 0) *cnt = 0;
    if (i >= 4096 * 20) return;
    const int b = i / 20;
    const int l = i - b * 20;
    if (l < lengths[b]) flags[ingrs[i]] = 1;
}

// assign compact slots (order irrelevant -> atomicAdd, no prefix sum)
__global__ void comp_assign(const int* __restrict__ flags, int* __restrict__ remap,
                            int* __restrict__ cnt)
{
    const int i = blockIdx.x * 256 + threadIdx.x;
    if (i < VOCAB && flags[i] == 1) remap[i] = atomicAdd(cnt, 1);
}

// ---------------- mega_prep: a1c | transpose W2 | transpose W3 | slots ------
// All four depend only on comp_assign output; fused to cut launches.

__device__ __forceinline__ void transpose_body(
    const float* __restrict__ in, unsigned short* __restrict__ out,
    int K, int Nin, int n0, int k0, int tid, float (*t)[65])
{
#pragma unroll
    for (int p = 0; p < 16; ++p) {
        const int lin = p * 256 + tid;
        const int kk = lin >> 6, nn = lin & 63;
        const int n = n0 + nn;
        t[kk][nn] = (n < Nin) ? in[(size_t)(k0 + kk) * Nin + n] : 0.f;
    }
    __syncthreads();
#pragma unroll
    for (int p = 0; p < 16; ++p) {
        const int lin = p * 256 + tid;
        const int nn = lin >> 6, kk = lin & 63;
        out[(size_t)(n0 + nn) * K + k0 + kk] = f2bf(t[kk][nn]);
    }
}

__global__ __launch_bounds__(256)
void mega_prep(const float* __restrict__ W1, const float* __restrict__ b1,
               const int* __restrict__ flags, const int* __restrict__ remap,
               unsigned short* __restrict__ A1,
               const float* __restrict__ W2, unsigned short* __restrict__ W2T,
               const float* __restrict__ W3, unsigned short* __restrict__ W3T,
               const int* __restrict__ ingrs, const int* __restrict__ lengths,
               int* __restrict__ slots)
{
    __shared__ float t[64][65];
    const int bid = blockIdx.x;
    const int tid = threadIdx.x;

    if (bid < 15000) {                       // prep_a1c: 2 vocab rows per block
        const int id = bid * 2 + (tid >> 7);
        if (flags[id] != 1) return;
        const int row = remap[id];
        const int k4  = (tid & 127) * 4;
        const float4 w  = *(const float4*)(W1 + (size_t)id * 512 + k4);
        const float4 bb = *(const float4*)(b1 + k4);
        unsigned short o[4];
        o[0] = f2bf(fmaxf(w.x + bb.x, 0.f));
        o[1] = f2bf(fmaxf(w.y + bb.y, 0.f));
        o[2] = f2bf(fmaxf(w.z + bb.z, 0.f));
        o[3] = f2bf(fmaxf(w.w + bb.w, 0.f));
        *(uint2*)(A1 + (size_t)row * 512 + k4) = *(const uint2*)o;
    } else if (bid < 15128) {                // W2 [512x1024] -> W2T [1024x512]
        const int local = bid - 15000;
        transpose_body(W2, W2T, 512, 1024, (local & 15) * 64, (local >> 4) * 64, tid, t);
    } else if (bid < 15640) {                // W3 [1024x2047] -> W3T [2048x1024]
        const int local = bid - 15128;
        transpose_body(W3, W3T, 1024, 2047, (local & 31) * 64, (local >> 5) * 64, tid, t);
    } else {                                 // slots[b,l] = remap[ingrs[b,l]]
        const int i = (bid - 15640) * 256 + tid;
        if (i >= 4096 * 20) return;
        const int b = i / 20;
        const int l = i - b * 20;
        if (l < lengths[b]) slots[i] = remap[ingrs[i]];
    }
}

// ---------------- bf16 MFMA GEMM, BK=64, XOR-swizzled LDS, M early-exit ----
// LDS-staged epilogue: C-tile round-trips through smem so global stores are
// 16 B/lane full-line dwordx4 (the per-element short stores caused ~2x
// FETCH_SIZE, suspected partial-line write-allocate).
__global__ __launch_bounds__(256)
void gemm_bf16(const unsigned short* __restrict__ A,
               const unsigned short* __restrict__ BT,
               const float* __restrict__ bias, int bias_n,
               unsigned short* __restrict__ C,
               int K, int N, int relu, const int* __restrict__ cnt)
{
    const int m0 = blockIdx.y * 128;
    const int mc = (*cnt + 127) & ~127;
    if (m0 >= mc) return;

    // union: K-loop uses 2 x 8192 shorts (As,Bs); epilogue uses 128 x 136
    __shared__ __align__(16) unsigned short smem[128 * 136];
    unsigned short* As = smem;
    unsigned short* Bs = smem + 8192;

    const int tid  = threadIdx.x;
    const int lane = tid & 63;
    const int wid  = tid >> 6;
    const int wr   = wid >> 1;          // wave row 0..1 (64-row span)
    const int wc   = wid & 1;           // wave col 0..1 (64-col span)
    const int n0   = blockIdx.x * 128;

    const int q  = lane >> 4;           // 0..3
    const int ml = lane & 15;

    f32x4 acc[4][4];
    const f32x4 zero = {0.f, 0.f, 0.f, 0.f};
#pragma unroll
    for (int i = 0; i < 4; ++i)
#pragma unroll
        for (int j = 0; j < 4; ++j) acc[i][j] = zero;

    // staging: wave w stages groups 4w..4w+3 (8 rows each) of A and of B.
    // LDS row r holds its 8 16-B k-chunks permuted: chunk kc at pos kc^(r&7).
    const int rg = lane >> 3;                    // row within group, 0..7
    const int kc = (lane & 7) ^ rg;              // swizzled global k-chunk
    const unsigned short* pA = A  + (size_t)(m0 + wid * 32 + rg) * K + kc * 8;
    const unsigned short* pB = BT + (size_t)(n0 + wid * 32 + rg) * K + kc * 8;
    unsigned short* lA = &As[wid * 4 * 512 + lane * 8];
    unsigned short* lB = &Bs[wid * 4 * 512 + lane * 8];

    // fragment-read swizzle: chunk index (k32*4+q) ^ (row&7), row&7 == ml&7
    const int swz0 = (q ^ (ml & 7)) * 8;         // k-half 0; ^32 elems for half 1

    for (int k0 = 0; k0 < K; k0 += 64) {
#pragma unroll
        for (int gg = 0; gg < 4; ++gg) {
            async16(pA + (size_t)gg * 8 * K + k0, lA + gg * 512);
            async16(pB + (size_t)gg * 8 * K + k0, lB + gg * 512);
        }
        __syncthreads();   // drains vmcnt -> LDS tiles ready

        bf16x8 af[4], bfr[4];
#pragma unroll
        for (int t = 0; t < 4; ++t) {
            af[t]  = *(const bf16x8*)&As[(wr * 64 + t * 16 + ml) * 64 + swz0];
            bfr[t] = *(const bf16x8*)&Bs[(wc * 64 + t * 16 + ml) * 64 + swz0];
        }
#pragma unroll
        for (int i = 0; i < 4; ++i)
#pragma unroll
            for (int j = 0; j < 4; ++j)
                acc[i][j] = __builtin_amdgcn_mfma_f32_16x16x32_bf16(
                    af[i], bfr[j], acc[i][j], 0, 0, 0);
#pragma unroll
        for (int t = 0; t < 4; ++t) {
            af[t]  = *(const bf16x8*)&As[(wr * 64 + t * 16 + ml) * 64 + (swz0 ^ 32)];
            bfr[t] = *(const bf16x8*)&Bs[(wc * 64 + t * 16 + ml) * 64 + (swz0 ^ 32)];
        }
#pragma unroll
        for (int i = 0; i < 4; ++i)
#pragma unroll
            for (int j = 0; j < 4; ++j)
                acc[i][j] = __builtin_amdgcn_mfma_f32_16x16x32_bf16(
                    af[i], bfr[j], acc[i][j], 0, 0, 0);

        __syncthreads();   // protect LDS before next stage (also guards epilogue reuse)
    }

    // ---- epilogue phase 1: bias/relu/round, write local tile to LDS ----
    // D layout: col = lane&15, row = (lane>>4)*4 + r  [m89/m91-verified]
    // row stride 136 shorts (16B-aligned rows; 4-bank rotation/row)
#pragma unroll
    for (int i = 0; i < 4; ++i) {
#pragma unroll
        for (int j = 0; j < 4; ++j) {
#pragma unroll
            for (int r = 0; r < 4; ++r) {
                const int rl = wr * 64 + i * 16 + q * 4 + r;
                const int cl = wc * 64 + j * 16 + ml;
                float v = acc[i][j][r];
                const int col = n0 + cl;
                v += (col < bias_n) ? bias[col] : 0.f;
                if (relu) v = fmaxf(v, 0.f);
                smem[rl * 136 + cl] = f2bf(v);
            }
        }
    }
    __syncthreads();
    // ---- epilogue phase 2: 16 B/lane coalesced stores (full 256B row spans) --
#pragma unroll
    for (int p = 0; p < 8; ++p) {
        const int rr = p * 16 + (tid >> 4);
        const int cc = tid & 15;
        const uint4 val = *(const uint4*)&smem[rr * 136 + cc * 8];
        *(uint4*)&C[(size_t)(m0 + rr) * N + n0 + cc * 8] = val;
    }
}

// ---------------- phase B: gather + in-block L2-normalize + masked sum -----
__global__ __launch_bounds__(256)
void gather_norm_sum(const int* __restrict__ lengths, const int* __restrict__ slots,
                     const unsigned short* __restrict__ Table, float* __restrict__ out)
{
    const int b    = blockIdx.x;
    const int tid  = threadIdx.x;
    const int lane = tid & 63;
    const int wid  = tid >> 6;
    __shared__ float red[4];

    float acc[8];
#pragma unroll
    for (int j = 0; j < 8; ++j) acc[j] = 0.f;

    const int len = lengths[b];   // uniform per block
    if (len > 0) {
        int slot = slots[b * 20];
        uint4 u = *((const uint4*)(Table + (size_t)slot * 2048) + tid);
        for (int l = 0; l < len; ++l) {
            const uint4 cu = u;
            if (l + 1 < len) {                       // prefetch next row
                const int ns = slots[b * 20 + l + 1];
                u = *((const uint4*)(Table + (size_t)ns * 2048) + tid);
            }
            float v[8];
            v[0] = bf2f(cu.x & 0xffffu); v[1] = bf2f(cu.x >> 16);
            v[2] = bf2f(cu.y & 0xffffu); v[3] = bf2f(cu.y >> 16);
            v[4] = bf2f(cu.z & 0xffffu); v[5] = bf2f(cu.z >> 16);
            v[6] = bf2f(cu.w & 0xffffu); v[7] = bf2f(cu.w >> 16);
            float s = 0.f;
#pragma unroll
            for (int j = 0; j < 8; ++j) s += v[j] * v[j];
#pragma unroll
            for (int off = 1; off < 64; off <<= 1) s += __shfl_xor(s, off, 64);
            if (lane == 0) red[wid] = s;
            __syncthreads();
            const float tot  = red[0] + red[1] + red[2] + red[3];
            const float invn = 1.0f / fmaxf(sqrtf(tot), 1e-12f);
            __syncthreads();   // red reused next iteration
#pragma unroll
            for (int j = 0; j < 8; ++j) acc[j] += v[j] * invn;
        }
    }

    const size_t base = (size_t)b * 2047;
#pragma unroll
    for (int j = 0; j < 8; ++j) {
        const int col = tid * 8 + j;
        if (col < 2047) out[base + col] = acc[j];
    }
}

// ---------------- launch ----------------

extern "C" void kernel_launch(void* const* d_in, const int* in_sizes, int n_in,
                              void* d_out, int out_size, void* d_ws, size_t ws_size,
                              hipStream_t stream)
{
    const int*   ingrs   = (const int*)d_in[0];
    const int*   lengths = (const int*)d_in[1];
    const float* W1 = (const float*)d_in[2];
    const float* b1 = (const float*)d_in[3];
    const float* W2 = (const float*)d_in[4];
    const float* b2 = (const float*)d_in[5];
    const float* W3 = (const float*)d_in[6];
    const float* b3 = (const float*)d_in[7];
    float* out = (float*)d_out;

    // ws layout (byte offsets, 16B-aligned):
    //   A1    [MPAD x 512]  bf16 :           0 ..  30,801,920
    //   H2    [MPAD x 1024] bf16 :  30,801,920 ..  92,405,760
    //   Table [MPAD x 2048] bf16 :  92,405,760 .. 215,613,440
    //   W2T   [1024 x 512]  bf16 : 215,613,440 .. 216,662,016
    //   W3T   [2048 x 1024] bf16 : 216,662,016 .. 220,856,320
    //   flags [VOCAB] int        : 220,856,320 .. 220,976,320
    //   remap [VOCAB] int        : 220,976,320 .. 221,096,320
    //   cnt   [1] int            : 221,096,320 .. 221,096,324
    //   slots [4096*20] int      : 221,216,448 .. 221,544,128
    char* ws = (char*)d_ws;
    unsigned short* A1    = (unsigned short*)(ws);
    unsigned short* H2    = (unsigned short*)(ws + 30801920);
    unsigned short* Table = (unsigned short*)(ws + 92405760);
    unsigned short* W2T   = (unsigned short*)(ws + 215613440);
    unsigned short* W3T   = (unsigned short*)(ws + 216662016);
    int*            flags = (int*)(ws + 220856320);
    int*            remap = (int*)(ws + 220976320);
    int*            cnt   = (int*)(ws + 221096320);
    int*            slots = (int*)(ws + 221216448);

    comp_mark  <<<(4096 * 20 + 255) / 256, 256, 0, stream>>>(ingrs, lengths, flags, cnt);
    comp_assign<<<(VOCAB + 255) / 256, 256, 0, stream>>>(flags, remap, cnt);
    // a1c (15000) | W2T (128) | W3T (512) | slots (320)
    mega_prep<<<15960, 256, 0, stream>>>(W1, b1, flags, remap, A1,
                                         W2, W2T, W3, W3T, ingrs, lengths, slots);

    // H2 = relu(A1 @ W2 + b2)   [mc x 1024]   (rows cnt..mc read poison A1: harmless)
    gemm_bf16<<<dim3(1024 / 128, MPAD / 128), 256, 0, stream>>>(
        A1, W2T, b2, 1024, H2, 512, 1024, 1, cnt);
    // Table = H2 @ W3 + b3      [mc x 2048] (col 2047 is zero pad)
    gemm_bf16<<<dim3(2048 / 128, MPAD / 128), 256, 0, stream>>>(
        H2, W3T, b3, 2047, Table, 1024, 2048, 0, cnt);

    gather_norm_sum<<<4096, 256, 0, stream>>>(lengths, slots, Table, out);
}

// Round 7
// 342.109 us; speedup vs baseline: 1.1478x; 1.0496x over previous
//
#include <hip/hip_runtime.h>

#define VOCAB 30000
#define MPAD  30080   // 235 * 128
#define MT_PAD 240    // m-tiles padded to multiple of 8 (XCD count)

typedef __attribute__((ext_vector_type(8))) short bf16x8;
typedef __attribute__((ext_vector_type(4))) float f32x4;

__device__ __forceinline__ unsigned short f2bf(float f) {
    unsigned int u = __builtin_bit_cast(unsigned int, f);
    u += 0x7fffu + ((u >> 16) & 1u);          // round-to-nearest-even
    return (unsigned short)(u >> 16);
}
__device__ __forceinline__ float bf2f(unsigned int h) {
    unsigned int u = h << 16;
    return __builtin_bit_cast(float, u);
}

__device__ __forceinline__ void async16(const void* g, void* l) {
    __builtin_amdgcn_global_load_lds(
        (__attribute__((address_space(1))) void*)g,
        (__attribute__((address_space(3))) void*)l, 16, 0, 0);
}

// ---------------- compaction ----------------
// flags relies on the harness's 0xAA ws poison: "marked" == exactly 1.
__global__ void comp_mark(const int* __restrict__ ingrs, const int* __restrict__ lengths,
                          int* __restrict__ flags, int* __restrict__ cnt)
{
    const int i = blockIdx.x * 256 + threadIdx.x;
    if (i == 0) *cnt = 0;
    if (i >= 4096 * 20) return;
    const int b = i / 20;
    const int l = i - b * 20;
    if (l < lengths[b]) flags[ingrs[i]] = 1;
}

// assign compact slots (order irrelevant -> atomicAdd, no prefix sum)
__global__ void comp_assign(const int* __restrict__ flags, int* __restrict__ remap,
                            int* __restrict__ cnt)
{
    const int i = blockIdx.x * 256 + threadIdx.x;
    if (i < VOCAB && flags[i] == 1) remap[i] = atomicAdd(cnt, 1);
}

// ---------------- mega_prep: a1c | transpose W2 | transpose W3 | slots ------

__device__ __forceinline__ void transpose_body(
    const float* __restrict__ in, unsigned short* __restrict__ out,
    int K, int Nin, int n0, int k0, int tid, float (*t)[65])
{
#pragma unroll
    for (int p = 0; p < 16; ++p) {
        const int lin = p * 256 + tid;
        const int kk = lin >> 6, nn = lin & 63;
        const int n = n0 + nn;
        t[kk][nn] = (n < Nin) ? in[(size_t)(k0 + kk) * Nin + n] : 0.f;
    }
    __syncthreads();
#pragma unroll
    for (int p = 0; p < 16; ++p) {
        const int lin = p * 256 + tid;
        const int nn = lin >> 6, kk = lin & 63;
        out[(size_t)(n0 + nn) * K + k0 + kk] = f2bf(t[kk][nn]);
    }
}

__global__ __launch_bounds__(256)
void mega_prep(const float* __restrict__ W1, const float* __restrict__ b1,
               const int* __restrict__ flags, const int* __restrict__ remap,
               unsigned short* __restrict__ A1,
               const float* __restrict__ W2, unsigned short* __restrict__ W2T,
               const float* __restrict__ W3, unsigned short* __restrict__ W3T,
               const int* __restrict__ ingrs, const int* __restrict__ lengths,
               int* __restrict__ slots)
{
    __shared__ float t[64][65];
    const int bid = blockIdx.x;
    const int tid = threadIdx.x;

    if (bid < 15000) {                       // prep_a1c: 2 vocab rows per block
        const int id = bid * 2 + (tid >> 7);
        if (flags[id] != 1) return;
        const int row = remap[id];
        const int k4  = (tid & 127) * 4;
        const float4 w  = *(const float4*)(W1 + (size_t)id * 512 + k4);
        const float4 bb = *(const float4*)(b1 + k4);
        unsigned short o[4];
        o[0] = f2bf(fmaxf(w.x + bb.x, 0.f));
        o[1] = f2bf(fmaxf(w.y + bb.y, 0.f));
        o[2] = f2bf(fmaxf(w.z + bb.z, 0.f));
        o[3] = f2bf(fmaxf(w.w + bb.w, 0.f));
        *(uint2*)(A1 + (size_t)row * 512 + k4) = *(const uint2*)o;
    } else if (bid < 15128) {                // W2 [512x1024] -> W2T [1024x512]
        const int local = bid - 15000;
        transpose_body(W2, W2T, 512, 1024, (local & 15) * 64, (local >> 4) * 64, tid, t);
    } else if (bid < 15640) {                // W3 [1024x2047] -> W3T [2048x1024]
        const int local = bid - 15128;
        transpose_body(W3, W3T, 1024, 2047, (local & 31) * 64, (local >> 5) * 64, tid, t);
    } else {                                 // slots[b,l] = remap[ingrs[b,l]]
        const int i = (bid - 15640) * 256 + tid;
        if (i >= 4096 * 20) return;
        const int b = i / 20;
        const int l = i - b * 20;
        if (l < lengths[b]) slots[i] = remap[ingrs[i]];
    }
}

// ---------------- bf16 MFMA GEMM, BK=64, XOR-swizzled LDS ----------------
// XCD-aware 1-D grid: id&7 selects XCD (dispatch round-robin heuristic);
// within an XCD the NT n-tiles of one m-tile are consecutive -> co-resident,
// so the A-panel is read 16x from that XCD's L2 instead of 16x from HBM.
// grid = MT_PAD * NT, NT = 1<<nt_shift. M early-exit via mc.
__global__ __launch_bounds__(256)
void gemm_bf16(const unsigned short* __restrict__ A,
               const unsigned short* __restrict__ BT,
               const float* __restrict__ bias, int bias_n,
               unsigned short* __restrict__ C,
               int K, int N, int relu, const int* __restrict__ cnt, int nt_shift)
{
    const int id = blockIdx.x;
    const int w  = id >> 3;
    const int n_tile = w & ((1 << nt_shift) - 1);
    const int m_tile = (id & 7) + ((w >> nt_shift) << 3);
    const int m0 = m_tile * 128;
    const int mc = (*cnt + 127) & ~127;
    if (m0 >= mc) return;
    const int n0 = n_tile * 128;

    // union: K-loop uses 2 x 8192 shorts (As,Bs); epilogue uses 128 x 136
    __shared__ __align__(16) unsigned short smem[128 * 136];
    unsigned short* As = smem;
    unsigned short* Bs = smem + 8192;

    const int tid  = threadIdx.x;
    const int lane = tid & 63;
    const int wid  = tid >> 6;
    const int wr   = wid >> 1;          // wave row 0..1 (64-row span)
    const int wc   = wid & 1;           // wave col 0..1 (64-col span)

    const int q  = lane >> 4;           // 0..3
    const int ml = lane & 15;

    f32x4 acc[4][4];
    const f32x4 zero = {0.f, 0.f, 0.f, 0.f};
#pragma unroll
    for (int i = 0; i < 4; ++i)
#pragma unroll
        for (int j = 0; j < 4; ++j) acc[i][j] = zero;

    // staging: wave w stages groups 4w..4w+3 (8 rows each) of A and of B.
    // LDS row r holds its 8 16-B k-chunks permuted: chunk kc at pos kc^(r&7).
    const int rg = lane >> 3;                    // row within group, 0..7
    const int kc = (lane & 7) ^ rg;              // swizzled global k-chunk
    const unsigned short* pA = A  + (size_t)(m0 + wid * 32 + rg) * K + kc * 8;
    const unsigned short* pB = BT + (size_t)(n0 + wid * 32 + rg) * K + kc * 8;
    unsigned short* lA = &As[wid * 4 * 512 + lane * 8];
    unsigned short* lB = &Bs[wid * 4 * 512 + lane * 8];

    // fragment-read swizzle: chunk index (k32*4+q) ^ (row&7), row&7 == ml&7
    const int swz0 = (q ^ (ml & 7)) * 8;         // k-half 0; ^32 elems for half 1

    for (int k0 = 0; k0 < K; k0 += 64) {
#pragma unroll
        for (int gg = 0; gg < 4; ++gg) {
            async16(pA + (size_t)gg * 8 * K, lA + gg * 512);
            async16(pB + (size_t)gg * 8 * K, lB + gg * 512);
        }
        pA += 64; pB += 64;
        __syncthreads();   // drains vmcnt -> LDS tiles ready

        bf16x8 af[4], bfr[4];
#pragma unroll
        for (int t = 0; t < 4; ++t) {
            af[t]  = *(const bf16x8*)&As[(wr * 64 + t * 16 + ml) * 64 + swz0];
            bfr[t] = *(const bf16x8*)&Bs[(wc * 64 + t * 16 + ml) * 64 + swz0];
        }
#pragma unroll
        for (int i = 0; i < 4; ++i)
#pragma unroll
            for (int j = 0; j < 4; ++j)
                acc[i][j] = __builtin_amdgcn_mfma_f32_16x16x32_bf16(
                    af[i], bfr[j], acc[i][j], 0, 0, 0);
#pragma unroll
        for (int t = 0; t < 4; ++t) {
            af[t]  = *(const bf16x8*)&As[(wr * 64 + t * 16 + ml) * 64 + (swz0 ^ 32)];
            bfr[t] = *(const bf16x8*)&Bs[(wc * 64 + t * 16 + ml) * 64 + (swz0 ^ 32)];
        }
#pragma unroll
        for (int i = 0; i < 4; ++i)
#pragma unroll
            for (int j = 0; j < 4; ++j)
                acc[i][j] = __builtin_amdgcn_mfma_f32_16x16x32_bf16(
                    af[i], bfr[j], acc[i][j], 0, 0, 0);

        __syncthreads();   // protect LDS before next stage (also guards epilogue reuse)
    }

    // ---- epilogue phase 1: bias/relu/round, write local tile to LDS ----
    // D layout: col = lane&15, row = (lane>>4)*4 + r  [m89/m91-verified]
#pragma unroll
    for (int i = 0; i < 4; ++i) {
#pragma unroll
        for (int j = 0; j < 4; ++j) {
#pragma unroll
            for (int r = 0; r < 4; ++r) {
                const int rl = wr * 64 + i * 16 + q * 4 + r;
                const int cl = wc * 64 + j * 16 + ml;
                float v = acc[i][j][r];
                const int col = n0 + cl;
                v += (col < bias_n) ? bias[col] : 0.f;
                if (relu) v = fmaxf(v, 0.f);
                smem[rl * 136 + cl] = f2bf(v);
            }
        }
    }
    __syncthreads();
    // ---- epilogue phase 2: 16 B/lane coalesced stores (full 256B row spans) --
#pragma unroll
    for (int p = 0; p < 8; ++p) {
        const int rr = p * 16 + (tid >> 4);
        const int cc = tid & 15;
        const uint4 val = *(const uint4*)&smem[rr * 136 + cc * 8];
        *(uint4*)&C[(size_t)(m0 + rr) * N + n0 + cc * 8] = val;
    }
}

// ---------------- phase B: gather + in-block L2-normalize + masked sum -----
__global__ __launch_bounds__(256)
void gather_norm_sum(const int* __restrict__ lengths, const int* __restrict__ slots,
                     const unsigned short* __restrict__ Table, float* __restrict__ out)
{
    const int b    = blockIdx.x;
    const int tid  = threadIdx.x;
    const int lane = tid & 63;
    const int wid  = tid >> 6;
    __shared__ float red[4];

    float acc[8];
#pragma unroll
    for (int j = 0; j < 8; ++j) acc[j] = 0.f;

    const int len = lengths[b];   // uniform per block
    if (len > 0) {
        int slot = slots[b * 20];
        uint4 u = *((const uint4*)(Table + (size_t)slot * 2048) + tid);
        for (int l = 0; l < len; ++l) {
            const uint4 cu = u;
            if (l + 1 < len) {                       // prefetch next row
                const int ns = slots[b * 20 + l + 1];
                u = *((const uint4*)(Table + (size_t)ns * 2048) + tid);
            }
            float v[8];
            v[0] = bf2f(cu.x & 0xffffu); v[1] = bf2f(cu.x >> 16);
            v[2] = bf2f(cu.y & 0xffffu); v[3] = bf2f(cu.y >> 16);
            v[4] = bf2f(cu.z & 0xffffu); v[5] = bf2f(cu.z >> 16);
            v[6] = bf2f(cu.w & 0xffffu); v[7] = bf2f(cu.w >> 16);
            float s = 0.f;
#pragma unroll
            for (int j = 0; j < 8; ++j) s += v[j] * v[j];
#pragma unroll
            for (int off = 1; off < 64; off <<= 1) s += __shfl_xor(s, off, 64);
            if (lane == 0) red[wid] = s;
            __syncthreads();
            const float tot  = red[0] + red[1] + red[2] + red[3];
            const float invn = 1.0f / fmaxf(sqrtf(tot), 1e-12f);
            __syncthreads();   // red reused next iteration
#pragma unroll
            for (int j = 0; j < 8; ++j) acc[j] += v[j] * invn;
        }
    }

    const size_t base = (size_t)b * 2047;
#pragma unroll
    for (int j = 0; j < 8; ++j) {
        const int col = tid * 8 + j;
        if (col < 2047) out[base + col] = acc[j];
    }
}

// ---------------- launch ----------------

extern "C" void kernel_launch(void* const* d_in, const int* in_sizes, int n_in,
                              void* d_out, int out_size, void* d_ws, size_t ws_size,
                              hipStream_t stream)
{
    const int*   ingrs   = (const int*)d_in[0];
    const int*   lengths = (const int*)d_in[1];
    const float* W1 = (const float*)d_in[2];
    const float* b1 = (const float*)d_in[3];
    const float* W2 = (const float*)d_in[4];
    const float* b2 = (const float*)d_in[5];
    const float* W3 = (const float*)d_in[6];
    const float* b3 = (const float*)d_in[7];
    float* out = (float*)d_out;

    // ws layout (byte offsets, 16B-aligned):
    //   A1    [MPAD x 512]  bf16 :           0 ..  30,801,920
    //   H2    [MPAD x 1024] bf16 :  30,801,920 ..  92,405,760
    //   Table [MPAD x 2048] bf16 :  92,405,760 .. 215,613,440
    //   W2T   [1024 x 512]  bf16 : 215,613,440 .. 216,662,016
    //   W3T   [2048 x 1024] bf16 : 216,662,016 .. 220,856,320
    //   flags [VOCAB] int        : 220,856,320 .. 220,976,320
    //   remap [VOCAB] int        : 220,976,320 .. 221,096,320
    //   cnt   [1] int            : 221,096,320 .. 221,096,324
    //   slots [4096*20] int      : 221,216,448 .. 221,544,128
    char* ws = (char*)d_ws;
    unsigned short* A1    = (unsigned short*)(ws);
    unsigned short* H2    = (unsigned short*)(ws + 30801920);
    unsigned short* Table = (unsigned short*)(ws + 92405760);
    unsigned short* W2T   = (unsigned short*)(ws + 215613440);
    unsigned short* W3T   = (unsigned short*)(ws + 216662016);
    int*            flags = (int*)(ws + 220856320);
    int*            remap = (int*)(ws + 220976320);
    int*            cnt   = (int*)(ws + 221096320);
    int*            slots = (int*)(ws + 221216448);

    comp_mark  <<<(4096 * 20 + 255) / 256, 256, 0, stream>>>(ingrs, lengths, flags, cnt);
    comp_assign<<<(VOCAB + 255) / 256, 256, 0, stream>>>(flags, remap, cnt);
    // a1c (15000) | W2T (128) | W3T (512) | slots (320)
    mega_prep<<<15960, 256, 0, stream>>>(W1, b1, flags, remap, A1,
                                         W2, W2T, W3, W3T, ingrs, lengths, slots);

    // H2 = relu(A1 @ W2 + b2)   [mc x 1024]; NT=8 n-tiles
    gemm_bf16<<<MT_PAD * 8, 256, 0, stream>>>(
        A1, W2T, b2, 1024, H2, 512, 1024, 1, cnt, 3);
    // Table = H2 @ W3 + b3      [mc x 2048]; NT=16 n-tiles
    gemm_bf16<<<MT_PAD * 16, 256, 0, stream>>>(
        H2, W3T, b3, 2047, Table, 1024, 2048, 0, cnt, 4);

    gather_norm_sum<<<4096, 256, 0, stream>>>(lengths, slots, Table, out);
}

// Round 8
// 328.466 us; speedup vs baseline: 1.1955x; 1.0415x over previous
//
#include <hip/hip_runtime.h>

#define VOCAB 30000
#define MPAD  30080   // 235 * 128
#define MT_PAD 240    // m-tiles padded to multiple of 8 (XCD count)

typedef __attribute__((ext_vector_type(8))) short bf16x8;
typedef __attribute__((ext_vector_type(4))) float f32x4;

__device__ __forceinline__ unsigned short f2bf(float f) {
    unsigned int u = __builtin_bit_cast(unsigned int, f);
    u += 0x7fffu + ((u >> 16) & 1u);          // round-to-nearest-even
    return (unsigned short)(u >> 16);
}
__device__ __forceinline__ float bf2f(unsigned int h) {
    unsigned int u = h << 16;
    return __builtin_bit_cast(float, u);
}

__device__ __forceinline__ void async16(const void* g, void* l) {
    __builtin_amdgcn_global_load_lds(
        (__attribute__((address_space(1))) void*)g,
        (__attribute__((address_space(3))) void*)l, 16, 0, 0);
}

// ---------------- compaction ----------------
// flags relies on the harness's 0xAA ws poison: "marked" == exactly 1.
__global__ void k_mark(const int* __restrict__ ingrs, const int* __restrict__ lengths,
                       int* __restrict__ flags, int* __restrict__ cnt)
{
    const int i = blockIdx.x * 256 + threadIdx.x;
    if (i == 0) *cnt = 0;
    if (i >= 4096 * 20) return;
    const int b = i / 20;
    const int l = i - b * 20;
    if (l < lengths[b]) flags[ingrs[i]] = 1;
}

__global__ void k_assign(const int* __restrict__ flags, int* __restrict__ remap,
                         int* __restrict__ cnt)
{
    const int i = blockIdx.x * 256 + threadIdx.x;
    if (i < VOCAB && flags[i] == 1) remap[i] = atomicAdd(cnt, 1);
}

// ---------------- shared device bodies ----------------

__device__ __forceinline__ void transpose_body(
    const float* __restrict__ in, unsigned short* __restrict__ out,
    int K, int Nin, int n0, int k0, int tid, float (*t)[65])
{
#pragma unroll
    for (int p = 0; p < 16; ++p) {
        const int lin = p * 256 + tid;
        const int kk = lin >> 6, nn = lin & 63;
        const int n = n0 + nn;
        t[kk][nn] = (n < Nin) ? in[(size_t)(k0 + kk) * Nin + n] : 0.f;
    }
    __syncthreads();
#pragma unroll
    for (int p = 0; p < 16; ++p) {
        const int lin = p * 256 + tid;
        const int nn = lin >> 6, kk = lin & 63;
        out[(size_t)(n0 + nn) * K + k0 + kk] = f2bf(t[kk][nn]);
    }
}

// m97-style BK=64 XOR-swizzled MFMA GEMM tile; id pre-swizzled by caller.
__device__ __forceinline__ void gemm_body(
    unsigned short* smem,
    const unsigned short* __restrict__ A, const unsigned short* __restrict__ BT,
    const float* __restrict__ bias, int bias_n, unsigned short* __restrict__ C,
    int K, int N, int relu, int mc, int id, int nt_shift)
{
    const int w  = id >> 3;
    const int n_tile = w & ((1 << nt_shift) - 1);
    const int m_tile = (id & 7) + ((w >> nt_shift) << 3);
    const int m0 = m_tile * 128;
    if (m0 >= mc) return;
    const int n0 = n_tile * 128;

    unsigned short* As = smem;
    unsigned short* Bs = smem + 8192;

    const int tid  = threadIdx.x;
    const int lane = tid & 63;
    const int wid  = tid >> 6;
    const int wr   = wid >> 1;
    const int wc   = wid & 1;
    const int q  = lane >> 4;
    const int ml = lane & 15;

    f32x4 acc[4][4];
    const f32x4 zero = {0.f, 0.f, 0.f, 0.f};
#pragma unroll
    for (int i = 0; i < 4; ++i)
#pragma unroll
        for (int j = 0; j < 4; ++j) acc[i][j] = zero;

    // staging: wave w stages groups 4w..4w+3 (8 rows each) of A and B.
    // LDS row r holds its 8 16-B k-chunks permuted: chunk kc at pos kc^(r&7).
    const int rg = lane >> 3;
    const int kc = (lane & 7) ^ rg;
    const unsigned short* pA = A  + (size_t)(m0 + wid * 32 + rg) * K + kc * 8;
    const unsigned short* pB = BT + (size_t)(n0 + wid * 32 + rg) * K + kc * 8;
    unsigned short* lA = &As[wid * 4 * 512 + lane * 8];
    unsigned short* lB = &Bs[wid * 4 * 512 + lane * 8];

    const int swz0 = (q ^ (ml & 7)) * 8;

    for (int k0 = 0; k0 < K; k0 += 64) {
#pragma unroll
        for (int gg = 0; gg < 4; ++gg) {
            async16(pA + (size_t)gg * 8 * K, lA + gg * 512);
            async16(pB + (size_t)gg * 8 * K, lB + gg * 512);
        }
        pA += 64; pB += 64;
        __syncthreads();

        bf16x8 af[4], bfr[4];
#pragma unroll
        for (int t = 0; t < 4; ++t) {
            af[t]  = *(const bf16x8*)&As[(wr * 64 + t * 16 + ml) * 64 + swz0];
            bfr[t] = *(const bf16x8*)&Bs[(wc * 64 + t * 16 + ml) * 64 + swz0];
        }
#pragma unroll
        for (int i = 0; i < 4; ++i)
#pragma unroll
            for (int j = 0; j < 4; ++j)
                acc[i][j] = __builtin_amdgcn_mfma_f32_16x16x32_bf16(
                    af[i], bfr[j], acc[i][j], 0, 0, 0);
#pragma unroll
        for (int t = 0; t < 4; ++t) {
            af[t]  = *(const bf16x8*)&As[(wr * 64 + t * 16 + ml) * 64 + (swz0 ^ 32)];
            bfr[t] = *(const bf16x8*)&Bs[(wc * 64 + t * 16 + ml) * 64 + (swz0 ^ 32)];
        }
#pragma unroll
        for (int i = 0; i < 4; ++i)
#pragma unroll
            for (int j = 0; j < 4; ++j)
                acc[i][j] = __builtin_amdgcn_mfma_f32_16x16x32_bf16(
                    af[i], bfr[j], acc[i][j], 0, 0, 0);

        __syncthreads();
    }

    // epilogue phase 1: bias/relu/round into LDS (stride 136 shorts)
#pragma unroll
    for (int i = 0; i < 4; ++i) {
#pragma unroll
        for (int j = 0; j < 4; ++j) {
#pragma unroll
            for (int r = 0; r < 4; ++r) {
                const int rl = wr * 64 + i * 16 + q * 4 + r;
                const int cl = wc * 64 + j * 16 + ml;
                float v = acc[i][j][r];
                const int col = n0 + cl;
                v += (col < bias_n) ? bias[col] : 0.f;
                if (relu) v = fmaxf(v, 0.f);
                smem[rl * 136 + cl] = f2bf(v);
            }
        }
    }
    __syncthreads();
    // epilogue phase 2: 16 B/lane coalesced stores
#pragma unroll
    for (int p = 0; p < 8; ++p) {
        const int rr = p * 16 + (tid >> 4);
        const int cc = tid & 15;
        const uint4 val = *(const uint4*)&smem[rr * 136 + cc * 8];
        *(uint4*)&C[(size_t)(m0 + rr) * N + n0 + cc * 8] = val;
    }
}

// ---------------- k_prep: A1 gather-activate | W2 transpose ----------------
__global__ __launch_bounds__(256)
void k_prep(const float* __restrict__ W1, const float* __restrict__ b1,
            const int* __restrict__ flags, const int* __restrict__ remap,
            unsigned short* __restrict__ A1,
            const float* __restrict__ W2, unsigned short* __restrict__ W2T)
{
    __shared__ float t[64][65];
    const int bid = blockIdx.x;
    const int tid = threadIdx.x;

    if (bid < 15000) {                       // 2 vocab rows per block
        const int id = bid * 2 + (tid >> 7);
        if (flags[id] != 1) return;
        const int row = remap[id];
        const int k4  = (tid & 127) * 4;
        const float4 w  = *(const float4*)(W1 + (size_t)id * 512 + k4);
        const float4 bb = *(const float4*)(b1 + k4);
        unsigned short o[4];
        o[0] = f2bf(fmaxf(w.x + bb.x, 0.f));
        o[1] = f2bf(fmaxf(w.y + bb.y, 0.f));
        o[2] = f2bf(fmaxf(w.z + bb.z, 0.f));
        o[3] = f2bf(fmaxf(w.w + bb.w, 0.f));
        *(uint2*)(A1 + (size_t)row * 512 + k4) = *(const uint2*)o;
    } else {                                 // W2 [512x1024] -> W2T [1024x512]
        const int local = bid - 15000;
        transpose_body(W2, W2T, 512, 1024, (local & 15) * 64, (local >> 4) * 64, tid, t);
    }
}

// ---------------- k_gemm1: GEMM1 + piggybacked W3 transpose + slots --------
__global__ __launch_bounds__(256)
void k_gemm1(const unsigned short* __restrict__ A1, const unsigned short* __restrict__ W2T,
             const float* __restrict__ b2, unsigned short* __restrict__ H2,
             const int* __restrict__ cnt,
             const float* __restrict__ W3, unsigned short* __restrict__ W3T,
             const int* __restrict__ ingrs, const int* __restrict__ lengths,
             const int* __restrict__ remap, int* __restrict__ slots)
{
    __shared__ __align__(16) unsigned short smem[128 * 136];
    const int bid = blockIdx.x;
    if (bid < MT_PAD * 8) {                  // GEMM1: H2 = relu(A1 @ W2 + b2)
        const int mc = (*cnt + 127) & ~127;
        gemm_body(smem, A1, W2T, b2, 1024, H2, 512, 1024, 1, mc, bid, 3);
    } else if (bid < MT_PAD * 8 + 512) {     // W3 [1024x2047] -> W3T [2048x1024]
        const int local = bid - MT_PAD * 8;
        transpose_body(W3, W3T, 1024, 2047, (local & 31) * 64, (local >> 5) * 64,
                       threadIdx.x, (float(*)[65])smem);
    } else {                                 // slots[b,l] = remap[ingrs[b,l]]
        const int i = (bid - (MT_PAD * 8 + 512)) * 256 + threadIdx.x;
        if (i < 4096 * 20) {
            const int b = i / 20;
            const int l = i - b * 20;
            if (l < lengths[b]) slots[i] = remap[ingrs[i]];
        }
    }
}

// ---------------- k_gemm2 ----------------
__global__ __launch_bounds__(256)
void k_gemm2(const unsigned short* __restrict__ H2, const unsigned short* __restrict__ W3T,
             const float* __restrict__ b3, unsigned short* __restrict__ Table,
             const int* __restrict__ cnt)
{
    __shared__ __align__(16) unsigned short smem[128 * 136];
    const int mc = (*cnt + 127) & ~127;
    gemm_body(smem, H2, W3T, b3, 2047, Table, 1024, 2048, 0, mc, blockIdx.x, 4);
}

// ---------------- k_gather: one wave per batch row, barrier-free ----------
// lane owns cols { (c*64+lane)*8 .. +8 } for c=0..3 (32 cols). Full-row norm
// via 6-step shfl_xor; no LDS, no __syncthreads.
__global__ __launch_bounds__(64)
void k_gather(const int* __restrict__ lengths, const int* __restrict__ slots,
              const unsigned short* __restrict__ Table, float* __restrict__ out)
{
    const int b    = blockIdx.x;
    const int lane = threadIdx.x;

    float acc[32];
#pragma unroll
    for (int j = 0; j < 32; ++j) acc[j] = 0.f;

    const int len = lengths[b];
    if (len > 0) {
        uint4 u[4];
        {
            const int slot = slots[b * 20];
            const uint4* rp = (const uint4*)(Table + (size_t)slot * 2048);
#pragma unroll
            for (int c = 0; c < 4; ++c) u[c] = rp[c * 64 + lane];
        }
        for (int l = 0; l < len; ++l) {
            uint4 cu[4];
#pragma unroll
            for (int c = 0; c < 4; ++c) cu[c] = u[c];
            if (l + 1 < len) {                       // prefetch next row
                const int ns = slots[b * 20 + l + 1];
                const uint4* rp = (const uint4*)(Table + (size_t)ns * 2048);
#pragma unroll
                for (int c = 0; c < 4; ++c) u[c] = rp[c * 64 + lane];
            }
            float v[32];
#pragma unroll
            for (int c = 0; c < 4; ++c) {
                v[c*8+0] = bf2f(cu[c].x & 0xffffu); v[c*8+1] = bf2f(cu[c].x >> 16);
                v[c*8+2] = bf2f(cu[c].y & 0xffffu); v[c*8+3] = bf2f(cu[c].y >> 16);
                v[c*8+4] = bf2f(cu[c].z & 0xffffu); v[c*8+5] = bf2f(cu[c].z >> 16);
                v[c*8+6] = bf2f(cu[c].w & 0xffffu); v[c*8+7] = bf2f(cu[c].w >> 16);
            }
            float s = 0.f;
#pragma unroll
            for (int j = 0; j < 32; ++j) s += v[j] * v[j];
#pragma unroll
            for (int off = 1; off < 64; off <<= 1) s += __shfl_xor(s, off, 64);
            const float invn = 1.0f / fmaxf(sqrtf(s), 1e-12f);
#pragma unroll
            for (int j = 0; j < 32; ++j) acc[j] += v[j] * invn;
        }
    }

    const size_t base = (size_t)b * 2047;
#pragma unroll
    for (int c = 0; c < 4; ++c) {
        const int col = (c * 64 + lane) * 8;
#pragma unroll
        for (int j = 0; j < 8; ++j)
            if (col + j < 2047) out[base + col + j] = acc[c * 8 + j];
    }
}

// ---------------- launch ----------------

extern "C" void kernel_launch(void* const* d_in, const int* in_sizes, int n_in,
                              void* d_out, int out_size, void* d_ws, size_t ws_size,
                              hipStream_t stream)
{
    const int*   ingrs   = (const int*)d_in[0];
    const int*   lengths = (const int*)d_in[1];
    const float* W1 = (const float*)d_in[2];
    const float* b1 = (const float*)d_in[3];
    const float* W2 = (const float*)d_in[4];
    const float* b2 = (const float*)d_in[5];
    const float* W3 = (const float*)d_in[6];
    const float* b3 = (const float*)d_in[7];
    float* out = (float*)d_out;

    // ws layout (byte offsets, 16B-aligned):
    //   A1    [MPAD x 512]  bf16 :           0 ..  30,801,920
    //   H2    [MPAD x 1024] bf16 :  30,801,920 ..  92,405,760
    //   Table [MPAD x 2048] bf16 :  92,405,760 .. 215,613,440
    //   W2T   [1024 x 512]  bf16 : 215,613,440 .. 216,662,016
    //   W3T   [2048 x 1024] bf16 : 216,662,016 .. 220,856,320
    //   flags [VOCAB] int        : 220,856,320 .. 220,976,320
    //   remap [VOCAB] int        : 220,976,320 .. 221,096,320
    //   cnt   [1] int            : 221,096,320 .. 221,096,324
    //   slots [4096*20] int      : 221,216,448 .. 221,544,128
    char* ws = (char*)d_ws;
    unsigned short* A1    = (unsigned short*)(ws);
    unsigned short* H2    = (unsigned short*)(ws + 30801920);
    unsigned short* Table = (unsigned short*)(ws + 92405760);
    unsigned short* W2T   = (unsigned short*)(ws + 215613440);
    unsigned short* W3T   = (unsigned short*)(ws + 216662016);
    int*            flags = (int*)(ws + 220856320);
    int*            remap = (int*)(ws + 220976320);
    int*            cnt   = (int*)(ws + 221096320);
    int*            slots = (int*)(ws + 221216448);

    k_mark  <<<(4096 * 20 + 255) / 256, 256, 0, stream>>>(ingrs, lengths, flags, cnt);
    k_assign<<<(VOCAB + 255) / 256, 256, 0, stream>>>(flags, remap, cnt);
    // a1c (15000) | W2T (128)
    k_prep<<<15128, 256, 0, stream>>>(W1, b1, flags, remap, A1, W2, W2T);
    // GEMM1 (1920 swizzled) | W3T transpose (512) | slots (320)
    k_gemm1<<<MT_PAD * 8 + 512 + 320, 256, 0, stream>>>(
        A1, W2T, b2, H2, cnt, W3, W3T, ingrs, lengths, remap, slots);
    // GEMM2: Table = H2 @ W3 + b3  (NT=16)
    k_gemm2<<<MT_PAD * 16, 256, 0, stream>>>(H2, W3T, b3, Table, cnt);

    k_gather<<<4096, 64, 0, stream>>>(lengths, slots, Table, out);
}